// Round 6
// baseline (544.987 us; speedup 1.0000x reference)
//
#include <hip/hip_runtime.h>
#include <hip/hip_bf16.h>

// LSTM_Actor v6: producer/consumer wave split.
// 256 blocks x 1024 threads (16 waves), 8 rows/block, persistent over t.
//  - H-waves (0-7): recurrent GEMM h@W_hh (hi/lo both sides, hi/lo packed in M,
//    8 MFMA/wave), shfl-reduce, activations, h hi/lo -> LDS (parity dbuf).
//  - X-waves (8-15): compute xpart(t+1) = x(t+1)@W_ih^T + bias ONE STEP AHEAD
//    (recurrence-free -> off critical path), writing fp32 LDS xpart[par^1].
//    A-frags built in registers from global x (2-step reg prefetch). Also the
//    output projection out[t-1] = h(t-1)@W_out^T (round-robin wave).
//  - ONE barrier/step: s_waitcnt lgkmcnt(0) + raw s_barrier. NO vmcnt drain
//    (hipcc's __syncthreads drains vmcnt(0) -> stalls on in-flight x prefetch).
// Accuracy: W_hh and h keep hi/lo (recurrent path); x, W_ih, W_out hi-only.

#define TT 512
#define BB 2048
#define DD 64
#define HH 64
#define AA 16

typedef short bf16x8 __attribute__((ext_vector_type(8)));
typedef float f32x4 __attribute__((ext_vector_type(4)));

#define MFMA16(a, b, c) __builtin_amdgcn_mfma_f32_16x16x32_bf16((a), (b), (c), 0, 0, 0)

#if defined(__has_builtin)
#  if __has_builtin(__builtin_amdgcn_exp2f)
#    define EXP2F(x) __builtin_amdgcn_exp2f(x)
#  else
#    define EXP2F(x) exp2f(x)
#  endif
#  if __has_builtin(__builtin_amdgcn_rcpf)
#    define RCPF(x) __builtin_amdgcn_rcpf(x)
#  else
#    define RCPF(x) (1.0f/(x))
#  endif
#else
#  define EXP2F(x) exp2f(x)
#  define RCPF(x) (1.0f/(x))
#endif

__device__ __forceinline__ float sigmoid_f(float x) {
  return RCPF(1.0f + EXP2F(-1.4426950408889634f * x));
}
__device__ __forceinline__ float tanh_f(float x) {
  return 1.0f - 2.0f * RCPF(1.0f + EXP2F(2.8853900817779268f * x));
}
__device__ __forceinline__ short f2bf(float f) {  // RNE fp32->bf16
  union { float f; unsigned u; } v; v.f = f;
  unsigned r = v.u + 0x7FFFu + ((v.u >> 16) & 1u);
  return (short)(r >> 16);
}
__device__ __forceinline__ float bf2f(short s) {
  union { unsigned u; float f; } v; v.u = ((unsigned)(unsigned short)s) << 16;
  return v.f;
}
__device__ __forceinline__ unsigned cvtpk2(float a, float b) {  // [b|a] packed bf16
  union { __hip_bfloat162 b2; unsigned u; } cv;
  cv.b2 = __float22bfloat162_rn(make_float2(a, b));
  return cv.u;
}

// lgkm-only barrier: LDS writes visible, global loads stay in flight.
__device__ __forceinline__ void block_sync_lds() {
  __builtin_amdgcn_sched_barrier(0);
  asm volatile("s_waitcnt lgkmcnt(0)" ::: "memory");
  __builtin_amdgcn_s_barrier();
  __builtin_amdgcn_sched_barrier(0);
}

// hbuf: 16 A-rows x 256B; per row [par0:64k x 2B | par1:...]; A-row 2r=hi(row r),
// 2r+1=lo. 16B-slot swizzle within 128B par region: slot ^= (Arow&7).
// xpart: [par][j:64][slot:8][q:4] fp32, slot = row ^ (j&7). gates i,f,g,o per (row,j).

__global__ __launch_bounds__(1024, 4)
void lstm_actor_v6(const float* __restrict__ x,
                   const float* __restrict__ W_ih,
                   const float* __restrict__ W_hh,
                   const float* __restrict__ b_ih,
                   const float* __restrict__ b_hh,
                   const float* __restrict__ W_out,
                   const float* __restrict__ b_out,
                   float* __restrict__ out) {
  __shared__ __align__(16) unsigned short hbuf[16 * 128];  // 4 KB
  __shared__ __align__(16) float xpart[2 * 64 * 8 * 4];    // 16 KB
  char* hb = (char*)hbuf;

  const int tid  = threadIdx.x;
  const int lane = tid & 63;
  const int w    = tid >> 6;        // 0..15
  const int lr   = lane & 15;
  const int lg   = lane >> 4;
  const int qq   = lr >> 3;         // 0/1
  const int jj   = lr & 7;
  const int r0   = blockIdx.x * 8;
  const bool hrole = (w < 8);
  const int  j0    = (hrole ? w : (w - 8)) * 8;   // j-slice of this wave

  // ---- shared-role B fragments (32 VGPR total, overlaid meanings) ----
  // hrole: Bh = W_hh hi, Bl = W_hh lo          (gate cols, k = h-dims)
  // xrole: Bh = W_ih hi; Bl[0][kt] = W_out hi (projection); Bl[1] = dup of Bh[1]
  bf16x8 Bh[2][2], Bl[2][2];
  float biasv0 = 0.f, biasv1 = 0.f, bo = 0.f;

  if (hrole) {
#pragma unroll
    for (int nt = 0; nt < 2; ++nt) {
      const int g = (nt * 2 + qq) * 64 + j0 + jj;
#pragma unroll
      for (int kt = 0; kt < 2; ++kt) {
        const float* src = W_hh + g * 64 + kt * 32 + lg * 8;
        bf16x8 vh, vl;
#pragma unroll
        for (int u = 0; u < 8; ++u) {
          const float f = src[u];
          const short hi = f2bf(f);
          vh[u] = hi;
          vl[u] = f2bf(f - bf2f(hi));
        }
        Bh[nt][kt] = vh; Bl[nt][kt] = vl;
      }
    }
  } else {
#pragma unroll
    for (int nt = 0; nt < 2; ++nt) {
      const int g = (nt * 2 + qq) * 64 + j0 + jj;
      const float bsum = b_ih[g] + b_hh[g];
      if (nt == 0) biasv0 = bsum; else biasv1 = bsum;
#pragma unroll
      for (int kt = 0; kt < 2; ++kt) {
        const float* src = W_ih + g * 64 + kt * 32 + lg * 8;
        bf16x8 vh;
#pragma unroll
        for (int u = 0; u < 8; ++u) vh[u] = f2bf(src[u]);
        Bh[nt][kt] = vh;
      }
    }
    bo = b_out[lr];
#pragma unroll
    for (int kt = 0; kt < 2; ++kt) {
      const float* src = W_out + lr * 64 + kt * 32 + lg * 8;
      bf16x8 vh;
#pragma unroll
      for (int u = 0; u < 8; ++u) vh[u] = f2bf(src[u]);
      Bl[0][kt] = vh;
      Bl[1][kt] = vh;  // keep defined
    }
  }

  // ---- h A-frag read offsets (byte): row lr, kt slot, + par*128 at runtime ----
  int aoff[2];
#pragma unroll
  for (int kt = 0; kt < 2; ++kt)
    aoff[kt] = lr * 256 + (((kt * 4 + lg) ^ (lr & 7)) << 4);

  // ---- h write geometry: lane owns (hrow = 2lg+qq, hj = j0+jj) ----
  const int hrow = 2 * lg + qq;
  const int hj   = j0 + jj;
  const int ar0  = 2 * hrow, ar1 = 2 * hrow + 1;
  const int hA_hi = ar0 * 256 + ((((hj >> 3) ^ (ar0 & 7))) << 4) + ((hj * 2) & 15);
  const int hA_lo = ar1 * 256 + ((((hj >> 3) ^ (ar1 & 7))) << 4) + ((hj * 2) & 15);
  // xpart read index (fp32 units), + par*2048 at runtime
  const int xpr = hj * 32 + ((hrow ^ (hj & 7)) << 2);

  // ---- zero hbuf (both parities; h(-1)=0) ----
  if (tid < 1024) ((unsigned*)hbuf)[tid] = 0u;

  // ---- X-role: x register prefetch state ----
  float4 xa0, xa1, xa2, xa3;   // x(t+1) : k = lg*8+{0..3},{4..7}, 32+lg*8+{0..3},{4..7}
  float4 xb0, xb1, xb2, xb3;   // x(t+2)
  xa0 = xa1 = xa2 = xa3 = make_float4(0.f, 0.f, 0.f, 0.f);
  xb0 = xb1 = xb2 = xb3 = xa0;
  const float* px_base = x + (size_t)(r0 + lr) * DD + lg * 8;  // valid only lr<8

  if (!hrole) {
    // prologue: xpart(0) from x(0); prefetch x(1), x(2)
    float4 c0v = xa0, c1v = xa0, c2v = xa0, c3v = xa0;
    if (lr < 8) {
      c0v = *(const float4*)(px_base);
      c1v = *(const float4*)(px_base + 4);
      c2v = *(const float4*)(px_base + 32);
      c3v = *(const float4*)(px_base + 36);
      xa0 = *(const float4*)(px_base + (size_t)1 * BB * DD);
      xa1 = *(const float4*)(px_base + (size_t)1 * BB * DD + 4);
      xa2 = *(const float4*)(px_base + (size_t)1 * BB * DD + 32);
      xa3 = *(const float4*)(px_base + (size_t)1 * BB * DD + 36);
      xb0 = *(const float4*)(px_base + (size_t)2 * BB * DD);
      xb1 = *(const float4*)(px_base + (size_t)2 * BB * DD + 4);
      xb2 = *(const float4*)(px_base + (size_t)2 * BB * DD + 32);
      xb3 = *(const float4*)(px_base + (size_t)2 * BB * DD + 36);
    }
    bf16x8 XA0, XA1;
    unsigned* u0 = (unsigned*)&XA0; unsigned* u1 = (unsigned*)&XA1;
    u0[0] = cvtpk2(c0v.x, c0v.y); u0[1] = cvtpk2(c0v.z, c0v.w);
    u0[2] = cvtpk2(c1v.x, c1v.y); u0[3] = cvtpk2(c1v.z, c1v.w);
    u1[0] = cvtpk2(c2v.x, c2v.y); u1[1] = cvtpk2(c2v.z, c2v.w);
    u1[2] = cvtpk2(c3v.x, c3v.y); u1[3] = cvtpk2(c3v.z, c3v.w);
    f32x4 xc0 = {0.f,0.f,0.f,0.f}, xc1 = xc0;
    xc0 = MFMA16(XA0, Bh[0][0], xc0); xc0 = MFMA16(XA1, Bh[0][1], xc0);
    xc1 = MFMA16(XA0, Bh[1][0], xc1); xc1 = MFMA16(XA1, Bh[1][1], xc1);
    if (lg < 2) {
      const int jx = j0 + jj;
      const int base = jx * 32;           // par 0
#pragma unroll
      for (int m = 0; m < 4; ++m) {
        const int row = lg * 4 + m;
        const int sl  = (row ^ (jx & 7)) << 2;
        xpart[base + sl + qq]     = xc0[m] + biasv0;
        xpart[base + sl + 2 + qq] = xc1[m] + biasv1;
      }
    }
  }

  float c_state = 0.0f;
  __syncthreads();

  for (int t = 0; t < TT; ++t) {
    const int par  = (t & 1) << 7;     // byte offset for hbuf par region
    const int parw = 128 - par;
    const int pxf  = (t & 1) << 11;    // fp32 offset for xpart par region
    const int pxw  = 2048 - pxf;

    if (hrole) {
      // ---- consume: h(t-1) frags + xpart(t) ----
      const f32x4 xp4 = *(const f32x4*)&xpart[pxf + xpr];
      const bf16x8 A2 = *(const bf16x8*)(hb + aoff[0] + par);
      const bf16x8 A3 = *(const bf16x8*)(hb + aoff[1] + par);

      f32x4 aH0 = {0.f,0.f,0.f,0.f}, aL0 = aH0, aH1 = aH0, aL1 = aH0;
      aH0 = MFMA16(A2, Bh[0][0], aH0); aH0 = MFMA16(A3, Bh[0][1], aH0);
      aL0 = MFMA16(A2, Bl[0][0], aL0); aL0 = MFMA16(A3, Bl[0][1], aL0);
      aH1 = MFMA16(A2, Bh[1][0], aH1); aH1 = MFMA16(A3, Bh[1][1], aH1);
      aL1 = MFMA16(A2, Bl[1][0], aL1); aL1 = MFMA16(A3, Bl[1][1], aL1);

      const f32x4 t0 = aH0 + aL0;
      const f32x4 t1 = aH1 + aL1;
      const float a0 = t0[0] + t0[1];   // row 2lg,   tile0
      const float b0 = t0[2] + t0[3];   // row 2lg+1, tile0
      const float a1 = t1[0] + t1[1];
      const float b1 = t1[2] + t1[3];
      const float rcv0 = __shfl_xor(qq ? a0 : b0, 8, 64);
      const float rcv1 = __shfl_xor(qq ? a1 : b1, 8, 64);
      const float iv_ = (qq ? rcv0 : a0) + xp4[0];
      const float fv_ = (qq ? b0 : rcv0) + xp4[1];
      const float gv_ = (qq ? rcv1 : a1) + xp4[2];
      const float ov_ = (qq ? b1 : rcv1) + xp4[3];

      const float iv = sigmoid_f(iv_);
      const float fv = sigmoid_f(fv_);
      const float gv = tanh_f(gv_);
      const float ov = sigmoid_f(ov_);
      c_state = fmaf(fv, c_state, iv * gv);
      const float h = ov * tanh_f(c_state);
      const short hh = f2bf(h);
      *(unsigned short*)(hb + hA_hi + parw) = (unsigned short)hh;
      *(unsigned short*)(hb + hA_lo + parw) = (unsigned short)f2bf(h - bf2f(hh));
    } else {
      // ---- produce xpart(t+1) from x(t+1) regs ----
      bf16x8 XA0, XA1;
      unsigned* u0 = (unsigned*)&XA0; unsigned* u1 = (unsigned*)&XA1;
      u0[0] = cvtpk2(xa0.x, xa0.y); u0[1] = cvtpk2(xa0.z, xa0.w);
      u0[2] = cvtpk2(xa1.x, xa1.y); u0[3] = cvtpk2(xa1.z, xa1.w);
      u1[0] = cvtpk2(xa2.x, xa2.y); u1[1] = cvtpk2(xa2.z, xa2.w);
      u1[2] = cvtpk2(xa3.x, xa3.y); u1[3] = cvtpk2(xa3.z, xa3.w);
      if (lr >= 8) { XA0 = (bf16x8)(short)0; XA1 = (bf16x8)(short)0; }

      f32x4 xc0 = {0.f,0.f,0.f,0.f}, xc1 = xc0;
      xc0 = MFMA16(XA0, Bh[0][0], xc0); xc0 = MFMA16(XA1, Bh[0][1], xc0);
      xc1 = MFMA16(XA0, Bh[1][0], xc1); xc1 = MFMA16(XA1, Bh[1][1], xc1);
      if (lg < 2) {
        const int jx = j0 + jj;
        const int base = pxw + jx * 32;
#pragma unroll
        for (int m = 0; m < 4; ++m) {
          const int row = lg * 4 + m;
          const int sl  = (row ^ (jx & 7)) << 2;
          xpart[base + sl + qq]     = xc0[m] + biasv0;
          xpart[base + sl + 2 + qq] = xc1[m] + biasv1;
        }
      }

      // ---- projection out[t-1] (round-robin X-wave) ----
      if (t > 0 && w == 8 + (t & 7)) {
        const bf16x8 P2 = *(const bf16x8*)(hb + aoff[0] + par);
        const bf16x8 P3 = *(const bf16x8*)(hb + aoff[1] + par);
        f32x4 pc = {0.f,0.f,0.f,0.f};
        pc = MFMA16(P2, Bl[0][0], pc);
        pc = MFMA16(P3, Bl[0][1], pc);
        const float oA = pc[0] + pc[1] + bo;
        const float oB = pc[2] + pc[3] + bo;
        const size_t basep = ((size_t)(t - 1) * BB + r0 + 2 * lg) * AA + lr;
        out[basep]      = oA;
        out[basep + AA] = oB;
      }

      // ---- rotate prefetch regs; issue x(t+3) loads (ride across barrier) ----
      xa0 = xb0; xa1 = xb1; xa2 = xb2; xa3 = xb3;
      if (t + 3 < TT && lr < 8) {
        const float* p3 = px_base + (size_t)(t + 3) * BB * DD;
        xb0 = *(const float4*)(p3);
        xb1 = *(const float4*)(p3 + 4);
        xb2 = *(const float4*)(p3 + 32);
        xb3 = *(const float4*)(p3 + 36);
      }
    }

    block_sync_lds();
  }

  // ---- epilogue: out[TT-1] from h(TT-1) in hbuf par 0 ----
  if (w == 8 + (TT & 7)) {
    const bf16x8 P2 = *(const bf16x8*)(hb + aoff[0]);
    const bf16x8 P3 = *(const bf16x8*)(hb + aoff[1]);
    f32x4 pc = {0.f,0.f,0.f,0.f};
    pc = MFMA16(P2, Bl[0][0], pc);
    pc = MFMA16(P3, Bl[0][1], pc);
    const float oA = pc[0] + pc[1] + bo;
    const float oB = pc[2] + pc[3] + bo;
    const size_t basep = ((size_t)(TT - 1) * BB + r0 + 2 * lg) * AA + lr;
    out[basep]      = oA;
    out[basep + AA] = oB;
  }
}

extern "C" void kernel_launch(void* const* d_in, const int* in_sizes, int n_in,
                              void* d_out, int out_size, void* d_ws, size_t ws_size,
                              hipStream_t stream) {
  const float* x     = (const float*)d_in[0];
  const float* W_ih  = (const float*)d_in[1];
  const float* W_hh  = (const float*)d_in[2];
  const float* b_ih  = (const float*)d_in[3];
  const float* b_hh  = (const float*)d_in[4];
  const float* W_out = (const float*)d_in[5];
  const float* b_out = (const float*)d_in[6];
  float* out = (float*)d_out;

  lstm_actor_v6<<<dim3(BB / 8), dim3(1024), 0, stream>>>(
      x, W_ih, W_hh, b_ih, b_hh, W_out, b_out, out);
}

// Round 7
// 287.405 us; speedup vs baseline: 1.8962x; 1.8962x over previous
//
#include <hip/hip_runtime.h>

// LSTM_Actor v7: v5 structure + lgkm-only barrier + chained-acc + x hi-only.
// 256 blocks x 512 threads (8 waves), 8 rows/block, persistent over t.
// Wave w owns j-slice [8w,8w+8) for ALL quadrants as 2 packed N-tiles:
//   tile0 cols {i,f}x8j, tile1 cols {g,o}x8j.
// A (M=16) = interleaved hi/lo: A-row 2r = hi(row r), 2r+1 = lo(row r).
//   x region: hi only (odd rows stay zero); h region: hi+lo (recurrent path).
// Gate GEMM: 12 MFMA/wave/step, ONE accumulator per tile (B-hi and B-lo
// chained; C accumulates across calls; pair-sum of C rows 2r/2r+1 yields the
// full (h_hi+h_lo)(W_hi+W_lo) product). Bias folded as 0.5x splat init.
// ONE lgkm-only barrier/step (s_waitcnt lgkmcnt(0) + s_barrier): x prefetch
// global loads stay in flight across the barrier (no vmcnt drain).
// Projection out[t-1] round-robins waves (w == t&7), W_out hi-only.

#define TT 512
#define BB 2048
#define DD 64
#define HH 64
#define AA 16

typedef short bf16x8 __attribute__((ext_vector_type(8)));
typedef float f32x4 __attribute__((ext_vector_type(4)));

#define MFMA16(a, b, c) __builtin_amdgcn_mfma_f32_16x16x32_bf16((a), (b), (c), 0, 0, 0)

#if defined(__has_builtin)
#  if __has_builtin(__builtin_amdgcn_exp2f)
#    define EXP2F(x) __builtin_amdgcn_exp2f(x)
#  else
#    define EXP2F(x) exp2f(x)
#  endif
#  if __has_builtin(__builtin_amdgcn_rcpf)
#    define RCPF(x) __builtin_amdgcn_rcpf(x)
#  else
#    define RCPF(x) (1.0f/(x))
#  endif
#else
#  define EXP2F(x) exp2f(x)
#  define RCPF(x) (1.0f/(x))
#endif

__device__ __forceinline__ float sigmoid_f(float x) {
  return RCPF(1.0f + EXP2F(-1.4426950408889634f * x));
}
__device__ __forceinline__ float tanh_f(float x) {
  return 1.0f - 2.0f * RCPF(1.0f + EXP2F(2.8853900817779268f * x));
}
__device__ __forceinline__ short f2bf(float f) {  // RNE fp32->bf16
  union { float f; unsigned u; } v; v.f = f;
  unsigned r = v.u + 0x7FFFu + ((v.u >> 16) & 1u);
  return (short)(r >> 16);
}
__device__ __forceinline__ float bf2f(short s) {
  union { unsigned u; float f; } v; v.u = ((unsigned)(unsigned short)s) << 16;
  return v.f;
}

// lgkm-only barrier: LDS writes visible; global loads stay in flight.
__device__ __forceinline__ void block_sync_lds() {
  __builtin_amdgcn_sched_barrier(0);
  asm volatile("s_waitcnt lgkmcnt(0)" ::: "memory");
  __builtin_amdgcn_s_barrier();
  __builtin_amdgcn_sched_barrier(0);
}

// act layout: 16 A-rows x 512 B. Per A-row: [x p0 0..127 | x p1 128..255 |
// h p0 256..383 | h p1 384..511]. 16B-slot XOR swizzle within each 128B
// region: slot' = slot ^ (Arow & 7).

__global__ __launch_bounds__(512, 2)
void lstm_actor_v7(const float* __restrict__ x,
                   const float* __restrict__ W_ih,
                   const float* __restrict__ W_hh,
                   const float* __restrict__ b_ih,
                   const float* __restrict__ b_hh,
                   const float* __restrict__ W_out,
                   const float* __restrict__ b_out,
                   float* __restrict__ out) {
  __shared__ __align__(16) unsigned short act[16 * 256];  // 8 KB
  char* actb = (char*)act;

  const int tid  = threadIdx.x;
  const int lane = tid & 63;
  const int w    = tid >> 6;       // wave 0..7: j-slice j0 = 8w; x-stage row w
  const int lr   = lane & 15;
  const int lg   = lane >> 4;
  const int qq   = lr >> 3;        // 0/1: quadrant within tile pair
  const int jj   = lr & 7;
  const int r0   = blockIdx.x * 8;
  const int j0   = w * 8;

  // ---- W_ih hi (k-tiles 0,1), W_hh hi+lo (k-tiles 2,3), per packed tile ----
  bf16x8 Bih[2][2], Bhh[2][2], Bhl[2][2];
  float biash[2];                  // 0.5*(b_ih+b_hh), folded into acc init
#pragma unroll
  for (int nt = 0; nt < 2; ++nt) {
    const int g = (nt * 2 + qq) * 64 + j0 + jj;
    biash[nt] = 0.5f * (b_ih[g] + b_hh[g]);
#pragma unroll
    for (int kt = 0; kt < 2; ++kt) {
      const float* si = W_ih + g * 64 + kt * 32 + lg * 8;
      const float* sh = W_hh + g * 64 + kt * 32 + lg * 8;
      bf16x8 vi, vh, vl;
#pragma unroll
      for (int u = 0; u < 8; ++u) {
        vi[u] = f2bf(si[u]);
        const float f = sh[u];
        const short hi = f2bf(f);
        vh[u] = hi;
        vl[u] = f2bf(f - bf2f(hi));
      }
      Bih[nt][kt] = vi; Bhh[nt][kt] = vh; Bhl[nt][kt] = vl;
    }
  }

  // ---- projection weights (all waves; hi only) ----
  bf16x8 pb[2];
  const float boh = 0.5f * b_out[lr];
#pragma unroll
  for (int kt = 0; kt < 2; ++kt) {
    const float* src = W_out + lr * 64 + kt * 32 + lg * 8;
    bf16x8 vh;
#pragma unroll
    for (int u = 0; u < 8; ++u) vh[u] = f2bf(src[u]);
    pb[kt] = vh;
  }

  // ---- zero LDS (x-lo rows and h(-1) stay/start zero) ----
  for (int i = tid; i < 16 * 256 / 2; i += 512) ((unsigned*)act)[i] = 0u;

  // ---- A-frag read offsets: row lr, kt in {0..3}; + par at runtime ----
  int aoff[4];
#pragma unroll
  for (int kt = 0; kt < 4; ++kt) {
    const int inner  = (kt & 1) * 64 + lg * 16;
    const int region = (kt < 2) ? 0 : 256;
    aoff[kt] = lr * 512 + region + ((((inner >> 4) ^ (lr & 7))) << 4);
  }

  // ---- x staging: wave w stages real row w (A-row 2w), hi only ----
  const int xs    = lane >> 3;
  const int xlow  = (2 * lane) & 15;
  const int xw_hi = (2 * w) * 512 + (((xs ^ ((2 * w) & 7))) << 4) + xlow;

  // ---- h write geometry: lane owns (hrow = 2lg+qq, hj = j0+jj) ----
  const int hrow = 2 * lg + qq;
  const int hj   = j0 + jj;
  const int ar0  = 2 * hrow, ar1 = 2 * hrow + 1;
  const int h_hi = ar0 * 512 + 256 + ((((hj >> 3) ^ (ar0 & 7))) << 4) + ((hj * 2) & 15);
  const int h_lo = ar1 * 512 + 256 + ((((hj >> 3) ^ (ar1 & 7))) << 4) + ((hj * 2) & 15);

  __syncthreads();

  // ---- stage x_0 (parity 0); prefetch x_1, x_2 into registers ----
  const float* xg0 = x + (size_t)(r0 + w) * DD + lane;
  *(unsigned short*)(actb + xw_hi) = (unsigned short)f2bf(*xg0);
  float xw_reg = xg0[(size_t)1 * BB * DD];
  float xf_reg = xg0[(size_t)2 * BB * DD];
  const float* xg = xg0 + (size_t)3 * BB * DD;

  float c_state = 0.0f;
  __syncthreads();

  for (int t = 0; t < TT; ++t) {
    const int par  = (t & 1) << 7;
    const int parw = 128 - par;

    // ---- A-frag reads (x_t | h_{t-1} at parity par) ----
    const bf16x8 A0 = *(const bf16x8*)(actb + aoff[0] + par);
    const bf16x8 A1 = *(const bf16x8*)(actb + aoff[1] + par);
    const bf16x8 A2 = *(const bf16x8*)(actb + aoff[2] + par);
    const bf16x8 A3 = *(const bf16x8*)(actb + aoff[3] + par);

    // ---- stage x_{t+1} into other parity (hi only) ----
    if (t + 1 < TT) {
      *(unsigned short*)(actb + xw_hi + parw) = (unsigned short)f2bf(xw_reg);
    }
    xw_reg = xf_reg;
    if (t + 3 < TT) xf_reg = *xg;
    xg += (size_t)BB * DD;

    // ---- gate GEMM: 12 MFMA, one chained acc per tile (x-first) ----
    f32x4 acc0 = {biash[0], biash[0], biash[0], biash[0]};
    f32x4 acc1 = {biash[1], biash[1], biash[1], biash[1]};
    acc0 = MFMA16(A0, Bih[0][0], acc0);  acc1 = MFMA16(A0, Bih[1][0], acc1);
    acc0 = MFMA16(A1, Bih[0][1], acc0);  acc1 = MFMA16(A1, Bih[1][1], acc1);
    acc0 = MFMA16(A2, Bhh[0][0], acc0);  acc1 = MFMA16(A2, Bhh[1][0], acc1);
    acc0 = MFMA16(A3, Bhh[0][1], acc0);  acc1 = MFMA16(A3, Bhh[1][1], acc1);
    acc0 = MFMA16(A2, Bhl[0][0], acc0);  acc1 = MFMA16(A2, Bhl[1][0], acc1);
    acc0 = MFMA16(A3, Bhl[0][1], acc0);  acc1 = MFMA16(A3, Bhl[1][1], acc1);

    // ---- projection for out[t-1] on wave (t&7): A2/A3 = hs[t-1] ----
    const bool do_proj = (w == (t & 7)) && (t > 0);
    f32x4 pacc = {boh, boh, boh, boh};
    if (do_proj) {
      pacc = MFMA16(A2, pb[0], pacc);
      pacc = MFMA16(A3, pb[1], pacc);
    }

    // ---- pair-sum (hi row + lo row) + shfl redistribution ----
    const float a0 = acc0[0] + acc0[1];   // row 2lg,   tile0
    const float b0 = acc0[2] + acc0[3];   // row 2lg+1, tile0
    const float a1 = acc1[0] + acc1[1];
    const float b1 = acc1[2] + acc1[3];
    const float rcv0 = __shfl_xor(qq ? a0 : b0, 8, 64);
    const float rcv1 = __shfl_xor(qq ? a1 : b1, 8, 64);
    const float iv_ = qq ? rcv0 : a0;
    const float fv_ = qq ? b0 : rcv0;
    const float gv_ = qq ? rcv1 : a1;
    const float ov_ = qq ? b1 : rcv1;

    // ---- elementwise: lane owns (hrow, hj) ----
    {
      const float iv = sigmoid_f(iv_);
      const float fv = sigmoid_f(fv_);
      const float gv = tanh_f(gv_);
      const float ov = sigmoid_f(ov_);
      c_state = fmaf(fv, c_state, iv * gv);
      const float h = ov * tanh_f(c_state);
      const short hh = f2bf(h);
      *(unsigned short*)(actb + h_hi + parw) = (unsigned short)hh;
      *(unsigned short*)(actb + h_lo + parw) = (unsigned short)f2bf(h - bf2f(hh));
    }

    // ---- projection stores (rows 2lg, 2lg+1; col lr) ----
    if (do_proj) {
      const float oA = pacc[0] + pacc[1];
      const float oB = pacc[2] + pacc[3];
      const size_t base = ((size_t)(t - 1) * BB + r0 + 2 * lg) * AA + lr;
      out[base]      = oA;
      out[base + AA] = oB;
    }

    block_sync_lds();
  }

  // ---- epilogue: out[TT-1] from final h (parity 0) ----
  if (w == (TT & 7)) {
    const bf16x8 A2 = *(const bf16x8*)(actb + aoff[2]);
    const bf16x8 A3 = *(const bf16x8*)(actb + aoff[3]);
    f32x4 pacc = {boh, boh, boh, boh};
    pacc = MFMA16(A2, pb[0], pacc);
    pacc = MFMA16(A3, pb[1], pacc);
    const float oA = pacc[0] + pacc[1];
    const float oB = pacc[2] + pacc[3];
    const size_t base = ((size_t)(TT - 1) * BB + r0 + 2 * lg) * AA + lr;
    out[base]      = oA;
    out[base + AA] = oB;
  }
}

extern "C" void kernel_launch(void* const* d_in, const int* in_sizes, int n_in,
                              void* d_out, int out_size, void* d_ws, size_t ws_size,
                              hipStream_t stream) {
  const float* x     = (const float*)d_in[0];
  const float* W_ih  = (const float*)d_in[1];
  const float* W_hh  = (const float*)d_in[2];
  const float* b_ih  = (const float*)d_in[3];
  const float* b_hh  = (const float*)d_in[4];
  const float* W_out = (const float*)d_in[5];
  const float* b_out = (const float*)d_in[6];
  float* out = (float*)d_out;

  lstm_actor_v7<<<dim3(BB / 8), dim3(512), 0, stream>>>(
      x, W_ih, W_hh, b_ih, b_hh, W_out, b_out, out);
}